// Round 2
// baseline (513.688 us; speedup 1.0000x reference)
//
#include <hip/hip_runtime.h>
#include <cstdint>

#define L_SEQ 2048
#define NB 4
#define EMB 1024
#define NHEAD 16
#define HD 64
#define M_ROWS (L_SEQ * NB)   // 8192
#define ANGC (1.5707963267948966f / 2048.0f)  // (pi/2)/m

typedef __bf16 bf16x8 __attribute__((ext_vector_type(8)));
typedef float f32x4 __attribute__((ext_vector_type(4)));

__device__ __forceinline__ unsigned short f2bf(float f) {
  unsigned int u = __float_as_uint(f);
  u += 0x7fffu + ((u >> 16) & 1u);   // round-to-nearest-even
  return (unsigned short)(u >> 16);
}

__device__ __forceinline__ void gload_lds16(const void* g, void* l) {
  __builtin_amdgcn_global_load_lds(
      (const __attribute__((address_space(1))) void*)g,
      (__attribute__((address_space(3))) void*)l, 16, 0, 0);
}

// ---------------- fp32 -> bf16 convert ----------------
__global__ __launch_bounds__(256) void cvt_bf16_kernel(
    const float* __restrict__ src, unsigned short* __restrict__ dst, int n8) {
  int i = blockIdx.x * 256 + threadIdx.x;
  if (i >= n8) return;
  const float4* s4 = (const float4*)src;
  float4 a = s4[i * 2], b = s4[i * 2 + 1];
  union { unsigned short u[8]; uint4 v; } o;
  o.u[0] = f2bf(a.x); o.u[1] = f2bf(a.y); o.u[2] = f2bf(a.z); o.u[3] = f2bf(a.w);
  o.u[4] = f2bf(b.x); o.u[5] = f2bf(b.y); o.u[6] = f2bf(b.z); o.u[7] = f2bf(b.w);
  *(uint4*)(dst + (size_t)i * 8) = o.v;
}

// ---------------- projection GEMM: C = X*W^T + b (optional relu) ----------------
// X: (8192,1024) bf16 row-major; W: (1024,1024) bf16 row-major (K contiguous both)
__global__ __launch_bounds__(256) void proj_gemm_kernel(
    const unsigned short* __restrict__ Xall, const unsigned short* __restrict__ Wall,
    const float* __restrict__ b0, const float* __restrict__ b1,
    const float* __restrict__ b2, float* __restrict__ Pall) {
  const int which = blockIdx.z;
  const unsigned short* Xb = Xall + (size_t)which * (M_ROWS * EMB);
  const unsigned short* Wb = Wall + (size_t)which * (EMB * EMB);
  const float* bias = (which == 0) ? b0 : (which == 1) ? b1 : b2;
  float* outp = Pall + (size_t)which * (M_ROWS * EMB);
  const bool relu = (which < 2);
  const int bm0 = blockIdx.x * 128;
  const int bn0 = blockIdx.y * 128;

  __shared__ unsigned short As[2][128 * 32];
  __shared__ unsigned short Bs[2][128 * 32];

  const int tid = threadIdx.x;
  const int lane = tid & 63, wave = tid >> 6;
  const int wrow = (wave >> 1) * 64, wcol = (wave & 1) * 64;
  const int fr = lane & 15, fk = lane >> 4;

  f32x4 acc[4][4];
#pragma unroll
  for (int m = 0; m < 4; ++m)
#pragma unroll
    for (int n = 0; n < 4; ++n) acc[m][n] = (f32x4){0.f, 0.f, 0.f, 0.f};

  auto stage = [&](int kt, int buf) {
#pragma unroll
    for (int i = 0; i < 2; ++i) {
      int c = i * 256 + wave * 64 + lane;
      int row = c >> 2;
      int kgs = (c & 3) ^ ((row >> 1) & 3);  // inverse XOR swizzle on SOURCE
      int ldsoff = (i * 256 + wave * 64) * 16;  // bytes; wave-uniform
      gload_lds16(Xb + (size_t)(bm0 + row) * EMB + kt * 32 + kgs * 8,
                  (char*)&As[buf][0] + ldsoff);
      gload_lds16(Wb + (size_t)(bn0 + row) * EMB + kt * 32 + kgs * 8,
                  (char*)&Bs[buf][0] + ldsoff);
    }
  };

  stage(0, 0);
  __syncthreads();
  const int NK = EMB / 32;
  for (int kt = 0; kt < NK; ++kt) {
    int buf = kt & 1;
    if (kt + 1 < NK) stage(kt + 1, buf ^ 1);
    bf16x8 af[4], bfr[4];
#pragma unroll
    for (int m = 0; m < 4; ++m) {
      int row = wrow + m * 16 + fr;
      af[m] = *(const bf16x8*)((const char*)&As[buf][0] + row * 64 +
                               ((fk ^ ((row >> 1) & 3)) * 16));
    }
#pragma unroll
    for (int n = 0; n < 4; ++n) {
      int row = wcol + n * 16 + fr;
      bfr[n] = *(const bf16x8*)((const char*)&Bs[buf][0] + row * 64 +
                                ((fk ^ ((row >> 1) & 3)) * 16));
    }
#pragma unroll
    for (int m = 0; m < 4; ++m)
#pragma unroll
      for (int n = 0; n < 4; ++n)
        acc[m][n] = __builtin_amdgcn_mfma_f32_16x16x32_bf16(af[m], bfr[n],
                                                            acc[m][n], 0, 0, 0);
    __syncthreads();
  }

#pragma unroll
  for (int n = 0; n < 4; ++n) {
    int gc = bn0 + wcol + n * 16 + fr;
    float bv = bias[gc];
#pragma unroll
    for (int m = 0; m < 4; ++m) {
#pragma unroll
      for (int r = 0; r < 4; ++r) {
        int gr = bm0 + wrow + m * 16 + fk * 4 + r;
        float v = acc[m][n][r] + bv;
        if (relu) v = fmaxf(v, 0.f);
        outp[(size_t)gr * EMB + gc] = v;
      }
    }
  }
}

// ---------------- phase 2: kv_[n,dd,m] and ksum[n,dd] ----------------
// kp/vp: (8192,1024) fp32 proj outputs. kv: (64,128,64), ksum: (64,128)
__global__ __launch_bounds__(256) void kv_kernel(
    const float* __restrict__ kp, const float* __restrict__ vp,
    float* __restrict__ kv, float* __restrict__ ksum) {
  const int n = blockIdx.y;
  const int nb = n >> 4, head = n & 15;
  const int l0 = blockIdx.x * 128;
  __shared__ float kt[32][64];
  __shared__ float vt[32][64];
  const int t = threadIdx.x;
  const int dg = t >> 3, mg = t & 7;

  float acc[4][8];
#pragma unroll
  for (int a = 0; a < 4; ++a)
#pragma unroll
    for (int b = 0; b < 8; ++b) acc[a][b] = 0.f;
  float ks[4] = {0.f, 0.f, 0.f, 0.f};

  for (int lt = l0; lt < l0 + 128; lt += 32) {
    {
      int i = t >> 3, c8 = (t & 7) * 8;
      const float* gk = kp + (size_t)((lt + i) * NB + nb) * EMB + head * HD + c8;
      const float* gv = vp + (size_t)((lt + i) * NB + nb) * EMB + head * HD + c8;
      *(float4*)&kt[i][c8] = *(const float4*)gk;
      *(float4*)&kt[i][c8 + 4] = *(const float4*)(gk + 4);
      *(float4*)&vt[i][c8] = *(const float4*)gv;
      *(float4*)&vt[i][c8 + 4] = *(const float4*)(gv + 4);
    }
    __syncthreads();
#pragma unroll 4
    for (int i = 0; i < 32; ++i) {
      int l = lt + i;
      float ang = ANGC * (float)(l + 1);
      float w = (dg < 16) ? __sinf(ang) : __cosf(ang);
      float4 kk4 = *(const float4*)&kt[i][(dg & 15) * 4];
      float kk[4];
      kk[0] = fmaxf(kk4.x, 0.f) * w; kk[1] = fmaxf(kk4.y, 0.f) * w;
      kk[2] = fmaxf(kk4.z, 0.f) * w; kk[3] = fmaxf(kk4.w, 0.f) * w;
      float4 v0 = *(const float4*)&vt[i][mg * 8];
      float4 v1 = *(const float4*)&vt[i][mg * 8 + 4];
      float vv[8] = {v0.x, v0.y, v0.z, v0.w, v1.x, v1.y, v1.z, v1.w};
#pragma unroll
      for (int a = 0; a < 4; ++a) {
#pragma unroll
        for (int b = 0; b < 8; ++b) acc[a][b] += kk[a] * vv[b];
        ks[a] += kk[a];
      }
    }
    __syncthreads();
  }

  float* kvn = kv + ((size_t)n * 128 + dg * 4) * 64 + mg * 8;
#pragma unroll
  for (int a = 0; a < 4; ++a)
#pragma unroll
    for (int b = 0; b < 8; ++b) atomicAdd(&kvn[(size_t)a * 64 + b], acc[a][b]);
  if (mg == 0) {
#pragma unroll
    for (int a = 0; a < 4; ++a) atomicAdd(&ksum[n * 128 + dg * 4 + a], ks[a]);
  }
}

// ---------------- phase 3: out[l,nb,head*64+m] = z * q_ . kv ----------------
__global__ __launch_bounds__(256) void out_kernel(
    const float* __restrict__ qp, const float* __restrict__ kv,
    const float* __restrict__ ksum, float* __restrict__ out) {
  const int n = blockIdx.y;
  const int nb = n >> 4, head = n & 15;
  const int L0 = blockIdx.x * 64;
  __shared__ float kvt[128][64];   // 32KB
  __shared__ float qt[64][68];     // padded stride 68
  __shared__ float kss[128];
  const int t = threadIdx.x;

  {  // load kv tile + ksum
    const float4* src = (const float4*)(kv + (size_t)n * 128 * 64);
    float4* dst = (float4*)&kvt[0][0];
#pragma unroll
    for (int j = 0; j < 8; ++j) dst[j * 256 + t] = src[j * 256 + t];
    if (t < 128) kss[t] = ksum[n * 128 + t];
  }
  {  // load q tile (relu applied, unweighted)
    int j = t >> 2, c16 = (t & 3) * 16;
    const float* gq = qp + (size_t)((L0 + j) * NB + nb) * EMB + head * HD + c16;
#pragma unroll
    for (int u = 0; u < 4; ++u) {
      float4 q4 = *(const float4*)(gq + u * 4);
      qt[j][c16 + u * 4 + 0] = fmaxf(q4.x, 0.f);
      qt[j][c16 + u * 4 + 1] = fmaxf(q4.y, 0.f);
      qt[j][c16 + u * 4 + 2] = fmaxf(q4.z, 0.f);
      qt[j][c16 + u * 4 + 3] = fmaxf(q4.w, 0.f);
    }
  }
  __syncthreads();

  const int lg = t >> 4, mg = t & 15;
  float sw[4], cw[4];
#pragma unroll
  for (int a = 0; a < 4; ++a) {
    float ang = ANGC * (float)(L0 + lg * 4 + a + 1);
    sw[a] = __sinf(ang);
    cw[a] = __cosf(ang);
  }

  f32x4 accs[4], accc[4];
  float dns[4] = {0, 0, 0, 0}, dnc[4] = {0, 0, 0, 0};
#pragma unroll
  for (int a = 0; a < 4; ++a) {
    accs[a] = (f32x4){0, 0, 0, 0};
    accc[a] = (f32x4){0, 0, 0, 0};
  }

#pragma unroll 4
  for (int c = 0; c < 64; ++c) {
    f32x4 kvs = *(const f32x4*)&kvt[c][mg * 4];
    f32x4 kvc = *(const f32x4*)&kvt[64 + c][mg * 4];
    float kssv = kss[c], kscv = kss[64 + c];
#pragma unroll
    for (int a = 0; a < 4; ++a) {
      float qv = qt[lg * 4 + a][c];
      accs[a] += qv * kvs;
      accc[a] += qv * kvc;
      dns[a] += qv * kssv;
      dnc[a] += qv * kscv;
    }
  }

#pragma unroll
  for (int a = 0; a < 4; ++a) {
    float den = sw[a] * dns[a] + cw[a] * dnc[a];
    float z = 1.f / fmaxf(den, 1e-4f);
    int l = L0 + lg * 4 + a;
    f32x4 o = (sw[a] * accs[a] + cw[a] * accc[a]) * z;
    *(f32x4*)&out[((size_t)l * NB + nb) * EMB + head * HD + mg * 4] = o;
  }
}

extern "C" void kernel_launch(void* const* d_in, const int* in_sizes, int n_in,
                              void* d_out, int out_size, void* d_ws, size_t ws_size,
                              hipStream_t stream) {
  const float* query = (const float*)d_in[0];
  const float* key = (const float*)d_in[1];
  const float* value = (const float*)d_in[2];
  const float* Wq = (const float*)d_in[3];
  const float* bq = (const float*)d_in[4];
  const float* Wk = (const float*)d_in[5];
  const float* bk = (const float*)d_in[6];
  const float* Wv = (const float*)d_in[7];
  const float* bv = (const float*)d_in[8];
  float* out = (float*)d_out;

  char* ws = (char*)d_ws;
  const size_t XN = (size_t)M_ROWS * EMB;  // 8388608
  const size_t WN = (size_t)EMB * EMB;     // 1048576
  // ws layout (bytes):
  //   xb:   3*XN*2  = 50331648   (bf16 query/key/value)
  //   wb:   3*WN*2  =  6291456   (bf16 Wq/Wk/Wv)
  //   proj: 3*XN*4  = 100663296  (f32 q/k/v projections)
  //   kvb:  64*128*64*4 = 2097152
  //   ksb:  64*128*4    =   32768
  const size_t need = 3 * XN * 2 + 3 * WN * 2 + 3 * XN * 4 +
                      (size_t)(64 * 128 * 64 + 64 * 128) * 4;
  if (ws_size < need) return;  // refuse to corrupt memory; clean test failure

  unsigned short* xb = (unsigned short*)ws;                      // 3*XN bf16
  unsigned short* wb = (unsigned short*)(ws + 3 * XN * 2);       // 3*WN bf16
  float* proj = (float*)(ws + 3 * XN * 2 + 3 * WN * 2);          // 3*XN f32
  float* kvb = (float*)(ws + 3 * XN * 2 + 3 * WN * 2 + 3 * XN * 4);
  float* ksb = kvb + 64 * 128 * 64;

  hipMemsetAsync(kvb, 0, (64 * 128 * 64 + 64 * 128) * sizeof(float), stream);

  const int NX8 = (int)(XN / 8), NW8 = (int)(WN / 8);
  cvt_bf16_kernel<<<NX8 / 256, 256, 0, stream>>>(query, xb + 0 * XN, NX8);
  cvt_bf16_kernel<<<NX8 / 256, 256, 0, stream>>>(key, xb + 1 * XN, NX8);
  cvt_bf16_kernel<<<NX8 / 256, 256, 0, stream>>>(value, xb + 2 * XN, NX8);
  cvt_bf16_kernel<<<NW8 / 256, 256, 0, stream>>>(Wq, wb + 0 * WN, NW8);
  cvt_bf16_kernel<<<NW8 / 256, 256, 0, stream>>>(Wk, wb + 1 * WN, NW8);
  cvt_bf16_kernel<<<NW8 / 256, 256, 0, stream>>>(Wv, wb + 2 * WN, NW8);

  proj_gemm_kernel<<<dim3(64, 8, 3), 256, 0, stream>>>(xb, wb, bq, bk, bv, proj);
  kv_kernel<<<dim3(16, 64), 256, 0, stream>>>(proj + 1 * XN, proj + 2 * XN, kvb, ksb);
  out_kernel<<<dim3(32, 64), 256, 0, stream>>>(proj, kvb, ksb, out);
}

// Round 5
// 352.983 us; speedup vs baseline: 1.4553x; 1.4553x over previous
//
#include <hip/hip_runtime.h>
#include <cstdint>

#define L_SEQ 2048
#define NB 4
#define EMB 1024
#define NHEAD 16
#define HD 64
#define M_ROWS (L_SEQ * NB)   // 8192
#define ANGC (1.5707963267948966f / 2048.0f)  // (pi/2)/m
#define NSPLIT 16

typedef __bf16 bf16x8 __attribute__((ext_vector_type(8)));
typedef float f32x4 __attribute__((ext_vector_type(4)));

__device__ __forceinline__ unsigned short f2bf(float f) {
  unsigned int u = __float_as_uint(f);
  u += 0x7fffu + ((u >> 16) & 1u);   // round-to-nearest-even
  return (unsigned short)(u >> 16);
}

__device__ __forceinline__ void gload_lds16(const void* g, void* l) {
  __builtin_amdgcn_global_load_lds(
      (const __attribute__((address_space(1))) void*)g,
      (__attribute__((address_space(3))) void*)l, 16, 0, 0);
}

// ---------------- fp32 -> bf16 convert ----------------
__global__ __launch_bounds__(256) void cvt_bf16_kernel(
    const float* __restrict__ src, unsigned short* __restrict__ dst, int n8) {
  int i = blockIdx.x * 256 + threadIdx.x;
  if (i >= n8) return;
  const float4* s4 = (const float4*)src;
  float4 a = s4[i * 2], b = s4[i * 2 + 1];
  union { unsigned short u[8]; uint4 v; } o;
  o.u[0] = f2bf(a.x); o.u[1] = f2bf(a.y); o.u[2] = f2bf(a.z); o.u[3] = f2bf(a.w);
  o.u[4] = f2bf(b.x); o.u[5] = f2bf(b.y); o.u[6] = f2bf(b.z); o.u[7] = f2bf(b.w);
  *(uint4*)(dst + (size_t)i * 8) = o.v;
}

// ---------------- projection GEMM: C = X*W^T + b (optional relu) ----------------
__global__ __launch_bounds__(256) void proj_gemm_kernel(
    const unsigned short* __restrict__ Xall, const unsigned short* __restrict__ Wall,
    const float* __restrict__ b0, const float* __restrict__ b1,
    const float* __restrict__ b2, float* __restrict__ Pall) {
  const int which = blockIdx.z;
  const unsigned short* Xb = Xall + (size_t)which * (M_ROWS * EMB);
  const unsigned short* Wb = Wall + (size_t)which * (EMB * EMB);
  const float* bias = (which == 0) ? b0 : (which == 1) ? b1 : b2;
  float* outp = Pall + (size_t)which * (M_ROWS * EMB);
  const bool relu = (which < 2);
  const int bm0 = blockIdx.x * 128;
  const int bn0 = blockIdx.y * 128;

  __shared__ unsigned short As[2][128 * 32];
  __shared__ unsigned short Bs[2][128 * 32];

  const int tid = threadIdx.x;
  const int lane = tid & 63, wave = tid >> 6;
  const int wrow = (wave >> 1) * 64, wcol = (wave & 1) * 64;
  const int fr = lane & 15, fk = lane >> 4;

  f32x4 acc[4][4];
#pragma unroll
  for (int m = 0; m < 4; ++m)
#pragma unroll
    for (int n = 0; n < 4; ++n) acc[m][n] = (f32x4){0.f, 0.f, 0.f, 0.f};

  auto stage = [&](int kt, int buf) {
#pragma unroll
    for (int i = 0; i < 2; ++i) {
      int c = i * 256 + wave * 64 + lane;
      int row = c >> 2;
      int kgs = (c & 3) ^ ((row >> 1) & 3);  // inverse XOR swizzle on SOURCE
      int ldsoff = (i * 256 + wave * 64) * 16;  // bytes; wave-uniform
      gload_lds16(Xb + (size_t)(bm0 + row) * EMB + kt * 32 + kgs * 8,
                  (char*)&As[buf][0] + ldsoff);
      gload_lds16(Wb + (size_t)(bn0 + row) * EMB + kt * 32 + kgs * 8,
                  (char*)&Bs[buf][0] + ldsoff);
    }
  };

  stage(0, 0);
  __syncthreads();
  const int NK = EMB / 32;
  for (int kt = 0; kt < NK; ++kt) {
    int buf = kt & 1;
    if (kt + 1 < NK) stage(kt + 1, buf ^ 1);
    bf16x8 af[4], bfr[4];
#pragma unroll
    for (int m = 0; m < 4; ++m) {
      int row = wrow + m * 16 + fr;
      af[m] = *(const bf16x8*)((const char*)&As[buf][0] + row * 64 +
                               ((fk ^ ((row >> 1) & 3)) * 16));
    }
#pragma unroll
    for (int n = 0; n < 4; ++n) {
      int row = wcol + n * 16 + fr;
      bfr[n] = *(const bf16x8*)((const char*)&Bs[buf][0] + row * 64 +
                                ((fk ^ ((row >> 1) & 3)) * 16));
    }
#pragma unroll
    for (int m = 0; m < 4; ++m)
#pragma unroll
      for (int n = 0; n < 4; ++n)
        acc[m][n] = __builtin_amdgcn_mfma_f32_16x16x32_bf16(af[m], bfr[n],
                                                            acc[m][n], 0, 0, 0);
    __syncthreads();
  }

#pragma unroll
  for (int n = 0; n < 4; ++n) {
    int gc = bn0 + wcol + n * 16 + fr;
    float bv = bias[gc];
#pragma unroll
    for (int m = 0; m < 4; ++m) {
#pragma unroll
      for (int r = 0; r < 4; ++r) {
        int gr = bm0 + wrow + m * 16 + fk * 4 + r;
        float v = acc[m][n][r] + bv;
        if (relu) v = fmaxf(v, 0.f);
        outp[(size_t)gr * EMB + gc] = v;
      }
    }
  }
}

// ---------------- phase 2a: per-split partial kv_[s,n,dd,m], ksum[s,n,dd] ----------------
// NO atomics: each (split, n) block owns its private output slice.
__global__ __launch_bounds__(256) void kv_part_kernel(
    const float* __restrict__ kp, const float* __restrict__ vp,
    float* __restrict__ kvpart, float* __restrict__ kspart) {
  const int n = blockIdx.y;
  const int s = blockIdx.x;
  const int nb = n >> 4, head = n & 15;
  const int l0 = s * (L_SEQ / NSPLIT);
  __shared__ float kt[32][64];
  __shared__ float vt[32][64];
  __shared__ float wt[2][32];
  const int t = threadIdx.x;
  const int dg = t >> 3, mg = t & 7;

  float acc[4][8];
#pragma unroll
  for (int a = 0; a < 4; ++a)
#pragma unroll
    for (int b = 0; b < 8; ++b) acc[a][b] = 0.f;
  float ks[4] = {0.f, 0.f, 0.f, 0.f};

  for (int lt = l0; lt < l0 + (L_SEQ / NSPLIT); lt += 32) {
    {
      int i = t >> 3, c8 = (t & 7) * 8;
      const float* gk = kp + (size_t)((lt + i) * NB + nb) * EMB + head * HD + c8;
      const float* gv = vp + (size_t)((lt + i) * NB + nb) * EMB + head * HD + c8;
      *(float4*)&kt[i][c8] = *(const float4*)gk;
      *(float4*)&kt[i][c8 + 4] = *(const float4*)(gk + 4);
      *(float4*)&vt[i][c8] = *(const float4*)gv;
      *(float4*)&vt[i][c8 + 4] = *(const float4*)(gv + 4);
    }
    if (t < 32) {  // hoist trig: 2 transcendentals per tile instead of 32/thread
      float ang = ANGC * (float)(lt + t + 1);
      wt[0][t] = __sinf(ang);
      wt[1][t] = __cosf(ang);
    }
    __syncthreads();
#pragma unroll 4
    for (int i = 0; i < 32; ++i) {
      float w = wt[dg >> 4][i];   // broadcast within wave
      float4 kk4 = *(const float4*)&kt[i][(dg & 15) * 4];
      float kk[4];
      kk[0] = fmaxf(kk4.x, 0.f) * w; kk[1] = fmaxf(kk4.y, 0.f) * w;
      kk[2] = fmaxf(kk4.z, 0.f) * w; kk[3] = fmaxf(kk4.w, 0.f) * w;
      float4 v0 = *(const float4*)&vt[i][mg * 8];
      float4 v1 = *(const float4*)&vt[i][mg * 8 + 4];
      float vv[8] = {v0.x, v0.y, v0.z, v0.w, v1.x, v1.y, v1.z, v1.w};
#pragma unroll
      for (int a = 0; a < 4; ++a) {
#pragma unroll
        for (int b = 0; b < 8; ++b) acc[a][b] += kk[a] * vv[b];
        ks[a] += kk[a];
      }
    }
    __syncthreads();
  }

  float* kvn = kvpart + ((size_t)(s * 64 + n) * 128 + dg * 4) * 64 + mg * 8;
#pragma unroll
  for (int a = 0; a < 4; ++a) {
    *(float4*)&kvn[(size_t)a * 64 + 0] = *(float4*)&acc[a][0];
    *(float4*)&kvn[(size_t)a * 64 + 4] = *(float4*)&acc[a][4];
  }
  if (mg == 0) {
#pragma unroll
    for (int a = 0; a < 4; ++a)
      kspart[(size_t)(s * 64 + n) * 128 + dg * 4 + a] = ks[a];
  }
}

// ---------------- phase 2b: reduce partials ----------------
// kvpart: NSPLIT x (64*128*64), kspart: NSPLIT x (64*128)
__global__ __launch_bounds__(256) void kv_reduce_kernel(
    const float* __restrict__ kvpart, const float* __restrict__ kspart,
    float* __restrict__ kv, float* __restrict__ ksum) {
  const int b = blockIdx.x;
  const int t = threadIdx.x;
  if (b < 512) {
    int idx = b * 256 + t;  // float4 index into 64*128*64/4 = 131072
    f32x4 sum = (f32x4){0, 0, 0, 0};
#pragma unroll
    for (int p = 0; p < NSPLIT; ++p)
      sum += ((const f32x4*)kvpart)[(size_t)p * 131072 + idx];
    ((f32x4*)kv)[idx] = sum;
  } else {
#pragma unroll
    for (int j = 0; j < 8; ++j) {
      int idx = j * 256 + t;  // float4 index into 64*128/4 = 2048
      f32x4 sum = (f32x4){0, 0, 0, 0};
#pragma unroll
      for (int p = 0; p < NSPLIT; ++p)
        sum += ((const f32x4*)kspart)[(size_t)p * 2048 + idx];
      ((f32x4*)ksum)[idx] = sum;
    }
  }
}

// ---------------- phase 3: out[l,nb,head*64+m] = z * q_ . kv ----------------
__global__ __launch_bounds__(256) void out_kernel(
    const float* __restrict__ qp, const float* __restrict__ kv,
    const float* __restrict__ ksum, float* __restrict__ out) {
  const int n = blockIdx.y;
  const int nb = n >> 4, head = n & 15;
  const int L0 = blockIdx.x * 64;
  __shared__ float kvt[128][64];   // 32KB
  __shared__ float qt[64][68];     // padded stride 68
  __shared__ float kss[128];
  const int t = threadIdx.x;

  {  // load kv tile + ksum
    const float4* src = (const float4*)(kv + (size_t)n * 128 * 64);
    float4* dst = (float4*)&kvt[0][0];
#pragma unroll
    for (int j = 0; j < 8; ++j) dst[j * 256 + t] = src[j * 256 + t];
    if (t < 128) kss[t] = ksum[n * 128 + t];
  }
  {  // load q tile (relu applied, unweighted)
    int j = t >> 2, c16 = (t & 3) * 16;
    const float* gq = qp + (size_t)((L0 + j) * NB + nb) * EMB + head * HD + c16;
#pragma unroll
    for (int u = 0; u < 4; ++u) {
      float4 q4 = *(const float4*)(gq + u * 4);
      qt[j][c16 + u * 4 + 0] = fmaxf(q4.x, 0.f);
      qt[j][c16 + u * 4 + 1] = fmaxf(q4.y, 0.f);
      qt[j][c16 + u * 4 + 2] = fmaxf(q4.z, 0.f);
      qt[j][c16 + u * 4 + 3] = fmaxf(q4.w, 0.f);
    }
  }
  __syncthreads();

  const int lg = t >> 4, mg = t & 15;
  float sw[4], cw[4];
#pragma unroll
  for (int a = 0; a < 4; ++a) {
    float ang = ANGC * (float)(L0 + lg * 4 + a + 1);
    sw[a] = __sinf(ang);
    cw[a] = __cosf(ang);
  }

  f32x4 accs[4], accc[4];
  float dns[4] = {0, 0, 0, 0}, dnc[4] = {0, 0, 0, 0};
#pragma unroll
  for (int a = 0; a < 4; ++a) {
    accs[a] = (f32x4){0, 0, 0, 0};
    accc[a] = (f32x4){0, 0, 0, 0};
  }

#pragma unroll 4
  for (int c = 0; c < 64; ++c) {
    f32x4 kvs = *(const f32x4*)&kvt[c][mg * 4];
    f32x4 kvc = *(const f32x4*)&kvt[64 + c][mg * 4];
    float kssv = kss[c], kscv = kss[64 + c];
#pragma unroll
    for (int a = 0; a < 4; ++a) {
      float qv = qt[lg * 4 + a][c];
      accs[a] += qv * kvs;
      accc[a] += qv * kvc;
      dns[a] += qv * kssv;
      dnc[a] += qv * kscv;
    }
  }

#pragma unroll
  for (int a = 0; a < 4; ++a) {
    float den = sw[a] * dns[a] + cw[a] * dnc[a];
    float z = 1.f / fmaxf(den, 1e-4f);
    int l = L0 + lg * 4 + a;
    f32x4 o = (sw[a] * accs[a] + cw[a] * accc[a]) * z;
    *(f32x4*)&out[((size_t)l * NB + nb) * EMB + head * HD + mg * 4] = o;
  }
}

extern "C" void kernel_launch(void* const* d_in, const int* in_sizes, int n_in,
                              void* d_out, int out_size, void* d_ws, size_t ws_size,
                              hipStream_t stream) {
  const float* query = (const float*)d_in[0];
  const float* key = (const float*)d_in[1];
  const float* value = (const float*)d_in[2];
  const float* Wq = (const float*)d_in[3];
  const float* bq = (const float*)d_in[4];
  const float* Wk = (const float*)d_in[5];
  const float* bk = (const float*)d_in[6];
  const float* Wv = (const float*)d_in[7];
  const float* bv = (const float*)d_in[8];
  float* out = (float*)d_out;

  char* ws = (char*)d_ws;
  const size_t XN = (size_t)M_ROWS * EMB;  // 8388608
  const size_t WN = (size_t)EMB * EMB;     // 1048576
  // ws layout (bytes):
  //   xb:   0         .. 50331648   (bf16 q/k/v inputs)     [dead after proj]
  //   wb:   50331648  .. 56623104   (bf16 Wq/Wk/Wv)         [dead after proj]
  //   proj: 56623104  .. 157286400  (f32 q/k/v projections)
  //   kvb:  157286400 .. 159383552
  //   ksb:  159383552 .. 159416320
  //   kvpart/kspart ALIAS xb (34 MB <= 50 MB, xb dead by then; same stream)
  const size_t need = 3 * XN * 2 + 3 * WN * 2 + 3 * XN * 4 +
                      (size_t)(64 * 128 * 64 + 64 * 128) * 4;
  if (ws_size < need) return;  // refuse to corrupt memory; clean test failure

  unsigned short* xb = (unsigned short*)ws;
  unsigned short* wb = (unsigned short*)(ws + 3 * XN * 2);
  float* proj = (float*)(ws + 3 * XN * 2 + 3 * WN * 2);
  float* kvb = (float*)(ws + 3 * XN * 2 + 3 * WN * 2 + 3 * XN * 4);
  float* ksb = kvb + 64 * 128 * 64;
  float* kvpart = (float*)ws;                       // 16*2MB = 32MB
  float* kspart = (float*)(ws + (size_t)NSPLIT * 64 * 128 * 64 * 4);  // 512KB

  const int NX8 = (int)(XN / 8), NW8 = (int)(WN / 8);
  cvt_bf16_kernel<<<NX8 / 256, 256, 0, stream>>>(query, xb + 0 * XN, NX8);
  cvt_bf16_kernel<<<NX8 / 256, 256, 0, stream>>>(key, xb + 1 * XN, NX8);
  cvt_bf16_kernel<<<NX8 / 256, 256, 0, stream>>>(value, xb + 2 * XN, NX8);
  cvt_bf16_kernel<<<NW8 / 256, 256, 0, stream>>>(Wq, wb + 0 * WN, NW8);
  cvt_bf16_kernel<<<NW8 / 256, 256, 0, stream>>>(Wk, wb + 1 * WN, NW8);
  cvt_bf16_kernel<<<NW8 / 256, 256, 0, stream>>>(Wv, wb + 2 * WN, NW8);

  proj_gemm_kernel<<<dim3(64, 8, 3), 256, 0, stream>>>(xb, wb, bq, bk, bv, proj);
  kv_part_kernel<<<dim3(NSPLIT, 64), 256, 0, stream>>>(proj + 1 * XN, proj + 2 * XN,
                                                       kvpart, kspart);
  kv_reduce_kernel<<<513, 256, 0, stream>>>(kvpart, kspart, kvb, ksb);
  out_kernel<<<dim3(32, 64), 256, 0, stream>>>(proj, kvb, ksb, out);
}

// Round 6
// 344.174 us; speedup vs baseline: 1.4925x; 1.0256x over previous
//
#include <hip/hip_runtime.h>
#include <cstdint>

#define L_SEQ 2048
#define NB 4
#define EMB 1024
#define NHEAD 16
#define HD 64
#define M_ROWS (L_SEQ * NB)   // 8192
#define ANGC (1.5707963267948966f / 2048.0f)  // (pi/2)/m
#define NSPLIT 16
#define XN ((size_t)M_ROWS * EMB)   // 8388608 = 2^23
#define WN ((size_t)EMB * EMB)      // 1048576 = 2^20
#define NX8 (1 << 20)               // XN/8
#define NW8 (1 << 17)               // WN/8

typedef __bf16 bf16x8 __attribute__((ext_vector_type(8)));
typedef float f32x4 __attribute__((ext_vector_type(4)));
typedef unsigned short u16x8 __attribute__((ext_vector_type(8)));

__device__ __forceinline__ unsigned short f2bf(float f) {
  unsigned int u = __float_as_uint(f);
  u += 0x7fffu + ((u >> 16) & 1u);   // round-to-nearest-even
  return (unsigned short)(u >> 16);
}
__device__ __forceinline__ float bf2f(unsigned short u) {
  return __uint_as_float((unsigned int)u << 16);
}

__device__ __forceinline__ void gload_lds16(const void* g, void* l) {
  __builtin_amdgcn_global_load_lds(
      (const __attribute__((address_space(1))) void*)g,
      (__attribute__((address_space(3))) void*)l, 16, 0, 0);
}

// ---------------- fp32 -> bf16 convert, ALL 6 tensors in one launch ----------------
__global__ __launch_bounds__(256) void cvt_all_kernel(
    const float* __restrict__ q, const float* __restrict__ k,
    const float* __restrict__ v, const float* __restrict__ wq,
    const float* __restrict__ wk, const float* __restrict__ wv,
    unsigned short* __restrict__ xb, unsigned short* __restrict__ wb) {
  int i = blockIdx.x * 256 + threadIdx.x;
  const float* src;
  unsigned short* dst;
  int off;
  if (i < 3 * NX8) {          // block-uniform: NX8 % 256 == 0
    int sel = i >> 20;
    off = i & (NX8 - 1);
    src = (sel == 0) ? q : (sel == 1) ? k : v;
    dst = xb + (size_t)sel * XN;
  } else {
    int j = i - 3 * NX8;      // block-uniform: NW8 % 256 == 0
    int sel = j >> 17;
    off = j & (NW8 - 1);
    src = (sel == 0) ? wq : (sel == 1) ? wk : wv;
    dst = wb + (size_t)sel * WN;
  }
  const float4* s4 = (const float4*)src;
  float4 a = s4[off * 2], b = s4[off * 2 + 1];
  union { unsigned short u[8]; uint4 vv; } o;
  o.u[0] = f2bf(a.x); o.u[1] = f2bf(a.y); o.u[2] = f2bf(a.z); o.u[3] = f2bf(a.w);
  o.u[4] = f2bf(b.x); o.u[5] = f2bf(b.y); o.u[6] = f2bf(b.z); o.u[7] = f2bf(b.w);
  *(uint4*)(dst + (size_t)off * 8) = o.vv;
}

// ---------------- projection GEMM: C = relu?(X*W^T + b), bf16 output ----------------
__global__ __launch_bounds__(256) void proj_gemm_kernel(
    const unsigned short* __restrict__ Xall, const unsigned short* __restrict__ Wall,
    const float* __restrict__ b0, const float* __restrict__ b1,
    const float* __restrict__ b2, unsigned short* __restrict__ Pall) {
  const int which = blockIdx.z;
  const unsigned short* Xb = Xall + (size_t)which * XN;
  const unsigned short* Wb = Wall + (size_t)which * WN;
  const float* bias = (which == 0) ? b0 : (which == 1) ? b1 : b2;
  unsigned short* outp = Pall + (size_t)which * XN;
  const bool relu = (which < 2);
  const int bm0 = blockIdx.x * 128;
  const int bn0 = blockIdx.y * 128;

  __shared__ unsigned short As[2][128 * 32];
  __shared__ unsigned short Bs[2][128 * 32];

  const int tid = threadIdx.x;
  const int lane = tid & 63, wave = tid >> 6;
  const int wrow = (wave >> 1) * 64, wcol = (wave & 1) * 64;
  const int fr = lane & 15, fk = lane >> 4;

  f32x4 acc[4][4];
#pragma unroll
  for (int m = 0; m < 4; ++m)
#pragma unroll
    for (int n = 0; n < 4; ++n) acc[m][n] = (f32x4){0.f, 0.f, 0.f, 0.f};

  auto stage = [&](int kt, int buf) {
#pragma unroll
    for (int i = 0; i < 2; ++i) {
      int c = i * 256 + wave * 64 + lane;
      int row = c >> 2;
      int kgs = (c & 3) ^ ((row >> 1) & 3);  // inverse XOR swizzle on SOURCE
      int ldsoff = (i * 256 + wave * 64) * 16;  // bytes; wave-uniform
      gload_lds16(Xb + (size_t)(bm0 + row) * EMB + kt * 32 + kgs * 8,
                  (char*)&As[buf][0] + ldsoff);
      gload_lds16(Wb + (size_t)(bn0 + row) * EMB + kt * 32 + kgs * 8,
                  (char*)&Bs[buf][0] + ldsoff);
    }
  };

  stage(0, 0);
  __syncthreads();
  const int NK = EMB / 32;
  for (int kt = 0; kt < NK; ++kt) {
    int buf = kt & 1;
    if (kt + 1 < NK) stage(kt + 1, buf ^ 1);
    bf16x8 af[4], bfr[4];
#pragma unroll
    for (int m = 0; m < 4; ++m) {
      int row = wrow + m * 16 + fr;
      af[m] = *(const bf16x8*)((const char*)&As[buf][0] + row * 64 +
                               ((fk ^ ((row >> 1) & 3)) * 16));
    }
#pragma unroll
    for (int n = 0; n < 4; ++n) {
      int row = wcol + n * 16 + fr;
      bfr[n] = *(const bf16x8*)((const char*)&Bs[buf][0] + row * 64 +
                                ((fk ^ ((row >> 1) & 3)) * 16));
    }
#pragma unroll
    for (int m = 0; m < 4; ++m)
#pragma unroll
      for (int n = 0; n < 4; ++n)
        acc[m][n] = __builtin_amdgcn_mfma_f32_16x16x32_bf16(af[m], bfr[n],
                                                            acc[m][n], 0, 0, 0);
    __syncthreads();
  }

#pragma unroll
  for (int n = 0; n < 4; ++n) {
    int gc = bn0 + wcol + n * 16 + fr;
    float bv = bias[gc];
#pragma unroll
    for (int m = 0; m < 4; ++m) {
#pragma unroll
      for (int r = 0; r < 4; ++r) {
        int gr = bm0 + wrow + m * 16 + fk * 4 + r;
        float v = acc[m][n][r] + bv;
        if (relu) v = fmaxf(v, 0.f);
        outp[(size_t)gr * EMB + gc] = f2bf(v);
      }
    }
  }
}

// ---------------- phase 2a: per-split partial kv_[s,n,dd,m], ksum[s,n,dd] ----------------
// kp/vp are bf16 proj outputs. NO atomics; fp32 accumulate.
__global__ __launch_bounds__(256) void kv_part_kernel(
    const unsigned short* __restrict__ kp, const unsigned short* __restrict__ vp,
    float* __restrict__ kvpart, float* __restrict__ kspart) {
  const int n = blockIdx.y;
  const int s = blockIdx.x;
  const int nb = n >> 4, head = n & 15;
  const int l0 = s * (L_SEQ / NSPLIT);
  __shared__ float kt[32][64];
  __shared__ float vt[32][64];
  __shared__ float wt[2][32];
  const int t = threadIdx.x;
  const int dg = t >> 3, mg = t & 7;

  float acc[4][8];
#pragma unroll
  for (int a = 0; a < 4; ++a)
#pragma unroll
    for (int b = 0; b < 8; ++b) acc[a][b] = 0.f;
  float ks[4] = {0.f, 0.f, 0.f, 0.f};

  for (int lt = l0; lt < l0 + (L_SEQ / NSPLIT); lt += 32) {
    {
      int i = t >> 3, c8 = (t & 7) * 8;
      u16x8 gk8 = *(const u16x8*)(kp + (size_t)((lt + i) * NB + nb) * EMB +
                                  head * HD + c8);
      u16x8 gv8 = *(const u16x8*)(vp + (size_t)((lt + i) * NB + nb) * EMB +
                                  head * HD + c8);
      float4 ka = {bf2f(gk8[0]), bf2f(gk8[1]), bf2f(gk8[2]), bf2f(gk8[3])};
      float4 kb = {bf2f(gk8[4]), bf2f(gk8[5]), bf2f(gk8[6]), bf2f(gk8[7])};
      float4 va = {bf2f(gv8[0]), bf2f(gv8[1]), bf2f(gv8[2]), bf2f(gv8[3])};
      float4 vb = {bf2f(gv8[4]), bf2f(gv8[5]), bf2f(gv8[6]), bf2f(gv8[7])};
      *(float4*)&kt[i][c8] = ka;
      *(float4*)&kt[i][c8 + 4] = kb;
      *(float4*)&vt[i][c8] = va;
      *(float4*)&vt[i][c8 + 4] = vb;
    }
    if (t < 32) {  // hoist trig: 2 transcendentals per tile
      float ang = ANGC * (float)(lt + t + 1);
      wt[0][t] = __sinf(ang);
      wt[1][t] = __cosf(ang);
    }
    __syncthreads();
#pragma unroll 4
    for (int i = 0; i < 32; ++i) {
      float w = wt[dg >> 4][i];   // broadcast within wave
      float4 kk4 = *(const float4*)&kt[i][(dg & 15) * 4];
      float kk[4];
      kk[0] = fmaxf(kk4.x, 0.f) * w; kk[1] = fmaxf(kk4.y, 0.f) * w;
      kk[2] = fmaxf(kk4.z, 0.f) * w; kk[3] = fmaxf(kk4.w, 0.f) * w;
      float4 v0 = *(const float4*)&vt[i][mg * 8];
      float4 v1 = *(const float4*)&vt[i][mg * 8 + 4];
      float vv[8] = {v0.x, v0.y, v0.z, v0.w, v1.x, v1.y, v1.z, v1.w};
#pragma unroll
      for (int a = 0; a < 4; ++a) {
#pragma unroll
        for (int b = 0; b < 8; ++b) acc[a][b] += kk[a] * vv[b];
        ks[a] += kk[a];
      }
    }
    __syncthreads();
  }

  float* kvn = kvpart + ((size_t)(s * 64 + n) * 128 + dg * 4) * 64 + mg * 8;
#pragma unroll
  for (int a = 0; a < 4; ++a) {
    *(float4*)&kvn[(size_t)a * 64 + 0] = *(float4*)&acc[a][0];
    *(float4*)&kvn[(size_t)a * 64 + 4] = *(float4*)&acc[a][4];
  }
  if (mg == 0) {
#pragma unroll
    for (int a = 0; a < 4; ++a)
      kspart[(size_t)(s * 64 + n) * 128 + dg * 4 + a] = ks[a];
  }
}

// ---------------- phase 2b: reduce partials ----------------
__global__ __launch_bounds__(256) void kv_reduce_kernel(
    const float* __restrict__ kvpart, const float* __restrict__ kspart,
    float* __restrict__ kv, float* __restrict__ ksum) {
  const int b = blockIdx.x;
  const int t = threadIdx.x;
  if (b < 512) {
    int idx = b * 256 + t;
    f32x4 sum = (f32x4){0, 0, 0, 0};
#pragma unroll
    for (int p = 0; p < NSPLIT; ++p)
      sum += ((const f32x4*)kvpart)[(size_t)p * 131072 + idx];
    ((f32x4*)kv)[idx] = sum;
  } else {
#pragma unroll
    for (int j = 0; j < 8; ++j) {
      int idx = j * 256 + t;
      f32x4 sum = (f32x4){0, 0, 0, 0};
#pragma unroll
      for (int p = 0; p < NSPLIT; ++p)
        sum += ((const f32x4*)kspart)[(size_t)p * 2048 + idx];
      ((f32x4*)ksum)[idx] = sum;
    }
  }
}

// ---------------- phase 3: out[l,nb,head*64+m] = z * q_ . kv (fp32 out) ----------------
__global__ __launch_bounds__(256) void out_kernel(
    const unsigned short* __restrict__ qp, const float* __restrict__ kv,
    const float* __restrict__ ksum, float* __restrict__ out) {
  const int n = blockIdx.y;
  const int nb = n >> 4, head = n & 15;
  const int L0 = blockIdx.x * 64;
  __shared__ float kvt[128][64];   // 32KB
  __shared__ float qt[64][68];     // padded stride 68
  __shared__ float kss[128];
  const int t = threadIdx.x;

  {  // load kv tile + ksum
    const float4* src = (const float4*)(kv + (size_t)n * 128 * 64);
    float4* dst = (float4*)&kvt[0][0];
#pragma unroll
    for (int j = 0; j < 8; ++j) dst[j * 256 + t] = src[j * 256 + t];
    if (t < 128) kss[t] = ksum[n * 128 + t];
  }
  {  // load q tile (bf16 -> f32, relu applied)
    int j = t >> 2, c16 = (t & 3) * 16;
    const unsigned short* gq =
        qp + (size_t)((L0 + j) * NB + nb) * EMB + head * HD + c16;
    u16x8 qa = *(const u16x8*)gq;
    u16x8 qb = *(const u16x8*)(gq + 8);
#pragma unroll
    for (int u = 0; u < 8; ++u) {
      qt[j][c16 + u] = fmaxf(bf2f(qa[u]), 0.f);
      qt[j][c16 + 8 + u] = fmaxf(bf2f(qb[u]), 0.f);
    }
  }
  __syncthreads();

  const int lg = t >> 4, mg = t & 15;
  float sw[4], cw[4];
#pragma unroll
  for (int a = 0; a < 4; ++a) {
    float ang = ANGC * (float)(L0 + lg * 4 + a + 1);
    sw[a] = __sinf(ang);
    cw[a] = __cosf(ang);
  }

  f32x4 accs[4], accc[4];
  float dns[4] = {0, 0, 0, 0}, dnc[4] = {0, 0, 0, 0};
#pragma unroll
  for (int a = 0; a < 4; ++a) {
    accs[a] = (f32x4){0, 0, 0, 0};
    accc[a] = (f32x4){0, 0, 0, 0};
  }

#pragma unroll 4
  for (int c = 0; c < 64; ++c) {
    f32x4 kvs = *(const f32x4*)&kvt[c][mg * 4];
    f32x4 kvc = *(const f32x4*)&kvt[64 + c][mg * 4];
    float kssv = kss[c], kscv = kss[64 + c];
#pragma unroll
    for (int a = 0; a < 4; ++a) {
      float qv = qt[lg * 4 + a][c];
      accs[a] += qv * kvs;
      accc[a] += qv * kvc;
      dns[a] += qv * kssv;
      dnc[a] += qv * kscv;
    }
  }

#pragma unroll
  for (int a = 0; a < 4; ++a) {
    float den = sw[a] * dns[a] + cw[a] * dnc[a];
    float z = 1.f / fmaxf(den, 1e-4f);
    int l = L0 + lg * 4 + a;
    f32x4 o = (sw[a] * accs[a] + cw[a] * accc[a]) * z;
    *(f32x4*)&out[((size_t)l * NB + nb) * EMB + head * HD + mg * 4] = o;
  }
}

extern "C" void kernel_launch(void* const* d_in, const int* in_sizes, int n_in,
                              void* d_out, int out_size, void* d_ws, size_t ws_size,
                              hipStream_t stream) {
  const float* query = (const float*)d_in[0];
  const float* key = (const float*)d_in[1];
  const float* value = (const float*)d_in[2];
  const float* Wq = (const float*)d_in[3];
  const float* bq = (const float*)d_in[4];
  const float* Wk = (const float*)d_in[5];
  const float* bk = (const float*)d_in[6];
  const float* Wv = (const float*)d_in[7];
  const float* bv = (const float*)d_in[8];
  float* out = (float*)d_out;

  char* ws = (char*)d_ws;
  // ws layout (bytes):
  //   xb:   0        .. 50331648   (bf16 q/k/v inputs)   [dead after proj]
  //   wb:   50331648 .. 56623104   (bf16 Wq/Wk/Wv)       [dead after proj]
  //   proj: 56623104 .. 106954752  (bf16 q/k/v projections)
  //   kvb:  106954752 .. 109051904 (f32)
  //   ksb:  109051904 .. 109084672 (f32)
  //   kvpart/kspart ALIAS xb (33 MB <= 50 MB, xb dead by then; same stream)
  const size_t need = 3 * XN * 2 + 3 * WN * 2 + 3 * XN * 2 +
                      (size_t)(64 * 128 * 64 + 64 * 128) * 4;
  if (ws_size < need) return;  // refuse to corrupt memory; clean test failure

  unsigned short* xb = (unsigned short*)ws;
  unsigned short* wb = (unsigned short*)(ws + 3 * XN * 2);
  unsigned short* proj = (unsigned short*)(ws + 3 * XN * 2 + 3 * WN * 2);
  float* kvb = (float*)(ws + 3 * XN * 2 + 3 * WN * 2 + 3 * XN * 2);
  float* ksb = kvb + 64 * 128 * 64;
  float* kvpart = (float*)ws;                                         // 32MB
  float* kspart = (float*)(ws + (size_t)NSPLIT * 64 * 128 * 64 * 4);  // 512KB

  const int total8 = 3 * NX8 + 3 * NW8;  // 3538944, divisible by 256
  cvt_all_kernel<<<total8 / 256, 256, 0, stream>>>(query, key, value, Wq, Wk, Wv,
                                                   xb, wb);
  proj_gemm_kernel<<<dim3(64, 8, 3), 256, 0, stream>>>(xb, wb, bq, bk, bv, proj);
  kv_part_kernel<<<dim3(NSPLIT, 64), 256, 0, stream>>>(proj + 1 * XN, proj + 2 * XN,
                                                       kvpart, kspart);
  kv_reduce_kernel<<<513, 256, 0, stream>>>(kvpart, kspart, kvb, ksb);
  out_kernel<<<dim3(32, 64), 256, 0, stream>>>(proj, kvb, ksb, out);
}

// Round 7
// 301.070 us; speedup vs baseline: 1.7062x; 1.1432x over previous
//
#include <hip/hip_runtime.h>
#include <cstdint>

#define L_SEQ 2048
#define NB 4
#define EMB 1024
#define NHEAD 16
#define HD 64
#define M_ROWS (L_SEQ * NB)   // 8192
#define ANGC (1.5707963267948966f / 2048.0f)  // (pi/2)/m
#define NSPLIT 16
#define XN ((size_t)M_ROWS * EMB)   // 8388608 = 2^23
#define WN ((size_t)EMB * EMB)      // 1048576 = 2^20
#define NX8 (1 << 20)               // XN/8
#define NW8 (1 << 17)               // WN/8

typedef __bf16 bf16x8 __attribute__((ext_vector_type(8)));
typedef float f32x4 __attribute__((ext_vector_type(4)));
typedef unsigned short u16x8 __attribute__((ext_vector_type(8)));

__device__ __forceinline__ unsigned short f2bf(float f) {
  unsigned int u = __float_as_uint(f);
  u += 0x7fffu + ((u >> 16) & 1u);   // round-to-nearest-even
  return (unsigned short)(u >> 16);
}
__device__ __forceinline__ float bf2f(unsigned short u) {
  return __uint_as_float((unsigned int)u << 16);
}

__device__ __forceinline__ void gload_lds16(const void* g, void* l) {
  __builtin_amdgcn_global_load_lds(
      (const __attribute__((address_space(1))) void*)g,
      (__attribute__((address_space(3))) void*)l, 16, 0, 0);
}

// ---------------- fp32 -> bf16 convert, ALL 6 tensors in one launch ----------------
__global__ __launch_bounds__(256) void cvt_all_kernel(
    const float* __restrict__ q, const float* __restrict__ k,
    const float* __restrict__ v, const float* __restrict__ wq,
    const float* __restrict__ wk, const float* __restrict__ wv,
    unsigned short* __restrict__ xb, unsigned short* __restrict__ wb) {
  int i = blockIdx.x * 256 + threadIdx.x;
  const float* src;
  unsigned short* dst;
  int off;
  if (i < 3 * NX8) {          // block-uniform: NX8 % 256 == 0
    int sel = i >> 20;
    off = i & (NX8 - 1);
    src = (sel == 0) ? q : (sel == 1) ? k : v;
    dst = xb + (size_t)sel * XN;
  } else {
    int j = i - 3 * NX8;      // block-uniform: NW8 % 256 == 0
    int sel = j >> 17;
    off = j & (NW8 - 1);
    src = (sel == 0) ? wq : (sel == 1) ? wk : wv;
    dst = wb + (size_t)sel * WN;
  }
  const float4* s4 = (const float4*)src;
  float4 a = s4[off * 2], b = s4[off * 2 + 1];
  union { unsigned short u[8]; uint4 vv; } o;
  o.u[0] = f2bf(a.x); o.u[1] = f2bf(a.y); o.u[2] = f2bf(a.z); o.u[3] = f2bf(a.w);
  o.u[4] = f2bf(b.x); o.u[5] = f2bf(b.y); o.u[6] = f2bf(b.z); o.u[7] = f2bf(b.w);
  *(uint4*)(dst + (size_t)off * 8) = o.vv;
}

// ---------------- projection GEMM: C = relu?(X*W^T + b), bf16 output ----------------
// Templated so each of q/k/v shows as a distinct kernel name in rocprof.
template <int WHICH>
__global__ __launch_bounds__(256) void proj_gemm_kernel(
    const unsigned short* __restrict__ Xall, const unsigned short* __restrict__ Wall,
    const float* __restrict__ bias, unsigned short* __restrict__ Pall) {
  const unsigned short* Xb = Xall + (size_t)WHICH * XN;
  const unsigned short* Wb = Wall + (size_t)WHICH * WN;
  unsigned short* outp = Pall + (size_t)WHICH * XN;
  const bool relu = (WHICH < 2);
  const int bm0 = blockIdx.x * 128;
  const int bn0 = blockIdx.y * 128;

  __shared__ unsigned short As[2][128 * 32];
  __shared__ unsigned short Bs[2][128 * 32];

  const int tid = threadIdx.x;
  const int lane = tid & 63, wave = tid >> 6;
  const int wrow = (wave >> 1) * 64, wcol = (wave & 1) * 64;
  const int fr = lane & 15, fk = lane >> 4;

  f32x4 acc[4][4];
#pragma unroll
  for (int m = 0; m < 4; ++m)
#pragma unroll
    for (int n = 0; n < 4; ++n) acc[m][n] = (f32x4){0.f, 0.f, 0.f, 0.f};

  auto stage = [&](int kt, int buf) {
#pragma unroll
    for (int i = 0; i < 2; ++i) {
      int c = i * 256 + wave * 64 + lane;
      int row = c >> 2;
      int kgs = (c & 3) ^ ((row >> 1) & 3);  // inverse XOR swizzle on SOURCE
      int ldsoff = (i * 256 + wave * 64) * 16;  // bytes; wave-uniform
      gload_lds16(Xb + (size_t)(bm0 + row) * EMB + kt * 32 + kgs * 8,
                  (char*)&As[buf][0] + ldsoff);
      gload_lds16(Wb + (size_t)(bn0 + row) * EMB + kt * 32 + kgs * 8,
                  (char*)&Bs[buf][0] + ldsoff);
    }
  };

  stage(0, 0);
  __syncthreads();
  const int NK = EMB / 32;
  for (int kt = 0; kt < NK; ++kt) {
    int buf = kt & 1;
    if (kt + 1 < NK) stage(kt + 1, buf ^ 1);
    bf16x8 af[4], bfr[4];
#pragma unroll
    for (int m = 0; m < 4; ++m) {
      int row = wrow + m * 16 + fr;
      af[m] = *(const bf16x8*)((const char*)&As[buf][0] + row * 64 +
                               ((fk ^ ((row >> 1) & 3)) * 16));
    }
#pragma unroll
    for (int n = 0; n < 4; ++n) {
      int row = wcol + n * 16 + fr;
      bfr[n] = *(const bf16x8*)((const char*)&Bs[buf][0] + row * 64 +
                                ((fk ^ ((row >> 1) & 3)) * 16));
    }
#pragma unroll
    for (int m = 0; m < 4; ++m)
#pragma unroll
      for (int n = 0; n < 4; ++n)
        acc[m][n] = __builtin_amdgcn_mfma_f32_16x16x32_bf16(af[m], bfr[n],
                                                            acc[m][n], 0, 0, 0);
    __syncthreads();
  }

#pragma unroll
  for (int n = 0; n < 4; ++n) {
    int gc = bn0 + wcol + n * 16 + fr;
    float bv = bias[gc];
#pragma unroll
    for (int m = 0; m < 4; ++m) {
#pragma unroll
      for (int r = 0; r < 4; ++r) {
        int gr = bm0 + wrow + m * 16 + fk * 4 + r;
        float v = acc[m][n][r] + bv;
        if (relu) v = fmaxf(v, 0.f);
        outp[(size_t)gr * EMB + gc] = f2bf(v);
      }
    }
  }
}

// ---------------- phase 2a: per-split partial kv_[s,n,dd,m], ksum[s,n,dd] ----------------
// kp/vp are bf16 proj outputs. NO atomics; fp32 accumulate. (unchanged this round)
__global__ __launch_bounds__(256) void kv_part_kernel(
    const unsigned short* __restrict__ kp, const unsigned short* __restrict__ vp,
    float* __restrict__ kvpart, float* __restrict__ kspart) {
  const int n = blockIdx.y;
  const int s = blockIdx.x;
  const int nb = n >> 4, head = n & 15;
  const int l0 = s * (L_SEQ / NSPLIT);
  __shared__ float kt[32][64];
  __shared__ float vt[32][64];
  __shared__ float wt[2][32];
  const int t = threadIdx.x;
  const int dg = t >> 3, mg = t & 7;

  float acc[4][8];
#pragma unroll
  for (int a = 0; a < 4; ++a)
#pragma unroll
    for (int b = 0; b < 8; ++b) acc[a][b] = 0.f;
  float ks[4] = {0.f, 0.f, 0.f, 0.f};

  for (int lt = l0; lt < l0 + (L_SEQ / NSPLIT); lt += 32) {
    {
      int i = t >> 3, c8 = (t & 7) * 8;
      u16x8 gk8 = *(const u16x8*)(kp + (size_t)((lt + i) * NB + nb) * EMB +
                                  head * HD + c8);
      u16x8 gv8 = *(const u16x8*)(vp + (size_t)((lt + i) * NB + nb) * EMB +
                                  head * HD + c8);
      float4 ka = {bf2f(gk8[0]), bf2f(gk8[1]), bf2f(gk8[2]), bf2f(gk8[3])};
      float4 kb = {bf2f(gk8[4]), bf2f(gk8[5]), bf2f(gk8[6]), bf2f(gk8[7])};
      float4 va = {bf2f(gv8[0]), bf2f(gv8[1]), bf2f(gv8[2]), bf2f(gv8[3])};
      float4 vb = {bf2f(gv8[4]), bf2f(gv8[5]), bf2f(gv8[6]), bf2f(gv8[7])};
      *(float4*)&kt[i][c8] = ka;
      *(float4*)&kt[i][c8 + 4] = kb;
      *(float4*)&vt[i][c8] = va;
      *(float4*)&vt[i][c8 + 4] = vb;
    }
    if (t < 32) {  // hoist trig: 2 transcendentals per tile
      float ang = ANGC * (float)(lt + t + 1);
      wt[0][t] = __sinf(ang);
      wt[1][t] = __cosf(ang);
    }
    __syncthreads();
#pragma unroll 4
    for (int i = 0; i < 32; ++i) {
      float w = wt[dg >> 4][i];   // broadcast within wave
      float4 kk4 = *(const float4*)&kt[i][(dg & 15) * 4];
      float kk[4];
      kk[0] = fmaxf(kk4.x, 0.f) * w; kk[1] = fmaxf(kk4.y, 0.f) * w;
      kk[2] = fmaxf(kk4.z, 0.f) * w; kk[3] = fmaxf(kk4.w, 0.f) * w;
      float4 v0 = *(const float4*)&vt[i][mg * 8];
      float4 v1 = *(const float4*)&vt[i][mg * 8 + 4];
      float vv[8] = {v0.x, v0.y, v0.z, v0.w, v1.x, v1.y, v1.z, v1.w};
#pragma unroll
      for (int a = 0; a < 4; ++a) {
#pragma unroll
        for (int b = 0; b < 8; ++b) acc[a][b] += kk[a] * vv[b];
        ks[a] += kk[a];
      }
    }
    __syncthreads();
  }

  float* kvn = kvpart + ((size_t)(s * 64 + n) * 128 + dg * 4) * 64 + mg * 8;
#pragma unroll
  for (int a = 0; a < 4; ++a) {
    *(float4*)&kvn[(size_t)a * 64 + 0] = *(float4*)&acc[a][0];
    *(float4*)&kvn[(size_t)a * 64 + 4] = *(float4*)&acc[a][4];
  }
  if (mg == 0) {
#pragma unroll
    for (int a = 0; a < 4; ++a)
      kspart[(size_t)(s * 64 + n) * 128 + dg * 4 + a] = ks[a];
  }
}

// ---------------- phase 2b: reduce partials -> kvT bf16 [n][m][dd] + ksum f32 ----------------
__global__ __launch_bounds__(256) void kv_reduce_kernel(
    const float* __restrict__ kvpart, const float* __restrict__ kspart,
    unsigned short* __restrict__ kvT, float* __restrict__ ksum) {
  const int n = blockIdx.x;
  const int t = threadIdx.x;
  __shared__ float kvsum[128][65];   // padded: transpose reads conflict-free

#pragma unroll
  for (int j = 0; j < 8; ++j) {
    int f4 = j * 256 + t;            // 0..2047
    int dd = f4 >> 4, m4 = f4 & 15;
    f32x4 s = (f32x4){0, 0, 0, 0};
#pragma unroll
    for (int p = 0; p < NSPLIT; ++p)
      s += *(const f32x4*)(kvpart + (((size_t)(p * 64 + n) * 128 + dd) * 64) +
                           m4 * 4);
    kvsum[dd][m4 * 4 + 0] = s[0];
    kvsum[dd][m4 * 4 + 1] = s[1];
    kvsum[dd][m4 * 4 + 2] = s[2];
    kvsum[dd][m4 * 4 + 3] = s[3];
  }
  if (t < 128) {
    float s = 0.f;
#pragma unroll
    for (int p = 0; p < NSPLIT; ++p) s += kspart[(size_t)(p * 64 + n) * 128 + t];
    ksum[n * 128 + t] = s;
  }
  __syncthreads();

  // transpose-write bf16 kvT[n][m][dd]
  int m = t >> 2, dseg = t & 3;
#pragma unroll
  for (int gg = 0; gg < 4; ++gg) {
    int dd0 = dseg * 32 + gg * 8;
    union { unsigned short u[8]; uint4 vv; } o;
#pragma unroll
    for (int e = 0; e < 8; ++e) o.u[e] = f2bf(kvsum[dd0 + e][m]);
    *(uint4*)(kvT + ((size_t)n * 64 + m) * 128 + dd0) = o.vv;
  }
}

// ---------------- phase 3 (MFMA): out[l,nb,head*64+m] = z * q_ . kv ----------------
// q_ staged bf16 (relu + sin/cos weights) in swizzled LDS; kvT bf16 [m][dd] = B operand.
__global__ __launch_bounds__(256) void out_mfma_kernel(
    const unsigned short* __restrict__ qp, const unsigned short* __restrict__ kvT,
    const float* __restrict__ ksum, float* __restrict__ out) {
  const int n = blockIdx.y;
  const int nb = n >> 4, head = n & 15;
  const int L0 = blockIdx.x * 64;
  const int t = threadIdx.x;
  const int lane = t & 63, wave = t >> 6;
  const int fr = lane & 15, fk = lane >> 4;

  __shared__ unsigned short q_lds[64 * 128];    // 16KB, granule-swizzled
  __shared__ unsigned short kvt_lds[64 * 128];  // 16KB, granule-swizzled
  __shared__ float ks_lds[128];
  __shared__ float z_lds[64];

  {  // stage q_: row j, 16 d per thread -> 4 granules (2 sin, 2 cos)
    int j = t >> 2, d0 = (t & 3) * 16;
    float ang = ANGC * (float)(L0 + j + 1);
    float sw = __sinf(ang), cw = __cosf(ang);
    const unsigned short* gq =
        qp + (size_t)((L0 + j) * NB + nb) * EMB + head * HD + d0;
    u16x8 qa = *(const u16x8*)gq;
    u16x8 qb = *(const u16x8*)(gq + 8);
    union { unsigned short u[8]; uint4 vv; } s0, s1, c0, c1;
#pragma unroll
    for (int e = 0; e < 8; ++e) {
      float fa = fmaxf(bf2f(qa[e]), 0.f);
      float fb = fmaxf(bf2f(qb[e]), 0.f);
      s0.u[e] = f2bf(fa * sw); s1.u[e] = f2bf(fb * sw);
      c0.u[e] = f2bf(fa * cw); c1.u[e] = f2bf(fb * cw);
    }
    int gs = (t & 3) * 2;  // granule base for sin part (dd = d0..d0+15)
    *(uint4*)&q_lds[(j * 16 + ((gs + 0) ^ (j & 7))) * 8] = s0.vv;
    *(uint4*)&q_lds[(j * 16 + ((gs + 1) ^ (j & 7))) * 8] = s1.vv;
    *(uint4*)&q_lds[(j * 16 + ((gs + 8) ^ (j & 7))) * 8] = c0.vv;
    *(uint4*)&q_lds[(j * 16 + ((gs + 9) ^ (j & 7))) * 8] = c1.vv;
  }
  {  // stage kvT[n]: 4 granules per thread, coalesced global reads
#pragma unroll
    for (int c = 0; c < 4; ++c) {
      int gi = t * 4 + c;
      int m = gi >> 4, g = gi & 15;
      uint4 v = *(const uint4*)(kvT + (size_t)n * 8192 + m * 128 + g * 8);
      *(uint4*)&kvt_lds[(m * 16 + (g ^ (m & 7))) * 8] = v;
    }
  }
  if (t < 128) ks_lds[t] = ksum[n * 128 + t];
  __syncthreads();

  // denominator: den[l] = sum_dd q_[l][dd] * ksum[dd]  (fp32)
  {
    int row = t >> 2, seg = t & 3;
    float sum = 0.f;
#pragma unroll
    for (int g8 = 0; g8 < 4; ++g8) {
      int g = seg * 4 + g8;
      const unsigned short* qg = &q_lds[(row * 16 + (g ^ (row & 7))) * 8];
      u16x8 qv = *(const u16x8*)qg;
#pragma unroll
      for (int e = 0; e < 8; ++e) sum += bf2f(qv[e]) * ks_lds[g * 8 + e];
    }
    sum += __shfl_xor(sum, 1);
    sum += __shfl_xor(sum, 2);
    if (seg == 0) z_lds[row] = 1.f / fmaxf(sum, 1e-4f);
  }

  // MFMA: wave w -> rows wrow..wrow+15, all 4 N-tiles
  const int wrow = wave * 16;
  f32x4 acc[4];
#pragma unroll
  for (int nt = 0; nt < 4; ++nt) acc[nt] = (f32x4){0, 0, 0, 0};
#pragma unroll
  for (int kk = 0; kk < 4; ++kk) {
    int arow = wrow + fr;
    bf16x8 af = *(const bf16x8*)&q_lds[(arow * 16 + ((kk * 4 + fk) ^ (arow & 7))) * 8];
#pragma unroll
    for (int nt = 0; nt < 4; ++nt) {
      int brow = nt * 16 + fr;
      bf16x8 bf =
          *(const bf16x8*)&kvt_lds[(brow * 16 + ((kk * 4 + fk) ^ (brow & 7))) * 8];
      acc[nt] = __builtin_amdgcn_mfma_f32_16x16x32_bf16(af, bf, acc[nt], 0, 0, 0);
    }
  }

  // epilogue: C row = fk*4+r (local), col m = nt*16+fr; multiply by z
#pragma unroll
  for (int nt = 0; nt < 4; ++nt) {
#pragma unroll
    for (int r = 0; r < 4; ++r) {
      int lrow = wrow + fk * 4 + r;
      int m = nt * 16 + fr;
      out[((size_t)(L0 + lrow) * NB + nb) * EMB + head * HD + m] =
          acc[nt][r] * z_lds[lrow];
    }
  }
}

extern "C" void kernel_launch(void* const* d_in, const int* in_sizes, int n_in,
                              void* d_out, int out_size, void* d_ws, size_t ws_size,
                              hipStream_t stream) {
  const float* query = (const float*)d_in[0];
  const float* key = (const float*)d_in[1];
  const float* value = (const float*)d_in[2];
  const float* Wq = (const float*)d_in[3];
  const float* bq = (const float*)d_in[4];
  const float* Wk = (const float*)d_in[5];
  const float* bk = (const float*)d_in[6];
  const float* Wv = (const float*)d_in[7];
  const float* bv = (const float*)d_in[8];
  float* out = (float*)d_out;

  char* ws = (char*)d_ws;
  // ws layout (bytes):
  //   xb:   0         .. 50331648   (bf16 q/k/v inputs)  [dead after proj]
  //   wb:   50331648  .. 56623104   (bf16 Wq/Wk/Wv)      [dead after proj]
  //   proj: 56623104  .. 106954752  (bf16 q/k/v projections)
  //   kvT:  106954752 .. 108003328  (bf16 [n][m][dd])
  //   ksb:  108003328 .. 108036096  (f32  [n][dd])
  //   kvpart/kspart ALIAS xb (34 MB <= 50 MB, xb dead by then; same stream)
  const size_t need = 3 * XN * 2 + 3 * WN * 2 + 3 * XN * 2 +
                      (size_t)64 * 64 * 128 * 2 + (size_t)64 * 128 * 4;
  if (ws_size < need) return;  // refuse to corrupt memory; clean test failure

  unsigned short* xb = (unsigned short*)ws;
  unsigned short* wb = (unsigned short*)(ws + 3 * XN * 2);
  unsigned short* proj = (unsigned short*)(ws + 3 * XN * 2 + 3 * WN * 2);
  unsigned short* kvT = (unsigned short*)(ws + 3 * XN * 2 + 3 * WN * 2 + 3 * XN * 2);
  float* ksb = (float*)(ws + 3 * XN * 2 + 3 * WN * 2 + 3 * XN * 2 +
                        (size_t)64 * 64 * 128 * 2);
  float* kvpart = (float*)ws;                                         // 32MB
  float* kspart = (float*)(ws + (size_t)NSPLIT * 64 * 128 * 64 * 4);  // 512KB

  const int total8 = 3 * NX8 + 3 * NW8;  // divisible by 256
  cvt_all_kernel<<<total8 / 256, 256, 0, stream>>>(query, key, value, Wq, Wk, Wv,
                                                   xb, wb);
  proj_gemm_kernel<0><<<dim3(64, 8), 256, 0, stream>>>(xb, wb, bq, proj);
  proj_gemm_kernel<1><<<dim3(64, 8), 256, 0, stream>>>(xb, wb, bk, proj);
  proj_gemm_kernel<2><<<dim3(64, 8), 256, 0, stream>>>(xb, wb, bv, proj);
  kv_part_kernel<<<dim3(NSPLIT, 64), 256, 0, stream>>>(proj + 1 * XN, proj + 2 * XN,
                                                       kvpart, kspart);
  kv_reduce_kernel<<<64, 256, 0, stream>>>(kvpart, kspart, kvT, ksb);
  out_mfma_kernel<<<dim3(32, 64), 256, 0, stream>>>(proj, kvT, ksb, out);
}

// Round 9
// 294.062 us; speedup vs baseline: 1.7469x; 1.0238x over previous
//
#include <hip/hip_runtime.h>
#include <cstdint>

#define L_SEQ 2048
#define NB 4
#define EMB 1024
#define NHEAD 16
#define HD 64
#define M_ROWS (L_SEQ * NB)   // 8192
#define ANGC (1.5707963267948966f / 2048.0f)  // (pi/2)/m
#define NSPLIT 16
#define XN ((size_t)M_ROWS * EMB)   // 8388608 = 2^23
#define WN ((size_t)EMB * EMB)      // 1048576 = 2^20
#define NX16 (1 << 19)              // XN/16
#define NW16 (1 << 16)              // WN/16

typedef __bf16 bf16x8 __attribute__((ext_vector_type(8)));
typedef float f32x4 __attribute__((ext_vector_type(4)));
typedef unsigned short u16x8 __attribute__((ext_vector_type(8)));

__device__ __forceinline__ unsigned short f2bf(float f) {
  unsigned int u = __float_as_uint(f);
  u += 0x7fffu + ((u >> 16) & 1u);   // round-to-nearest-even
  return (unsigned short)(u >> 16);
}
__device__ __forceinline__ float bf2f(unsigned short u) {
  return __uint_as_float((unsigned int)u << 16);
}

__device__ __forceinline__ void gload_lds16(const void* g, void* l) {
  __builtin_amdgcn_global_load_lds(
      (const __attribute__((address_space(1))) void*)g,
      (__attribute__((address_space(3))) void*)l, 16, 0, 0);
}

// ---------------- fp32 -> bf16 convert, 16 floats/thread (4 loads in flight) ----------------
__global__ __launch_bounds__(256) void cvt_all_kernel(
    const float* __restrict__ q, const float* __restrict__ k,
    const float* __restrict__ v, const float* __restrict__ wq,
    const float* __restrict__ wk, const float* __restrict__ wv,
    unsigned short* __restrict__ xb, unsigned short* __restrict__ wb) {
  int i = blockIdx.x * 256 + threadIdx.x;
  const float* src;
  unsigned short* dst;
  size_t off;
  if (i < 3 * NX16) {          // block-uniform: NX16 % 256 == 0
    int sel = i >> 19;
    off = (size_t)(i & (NX16 - 1));
    src = (sel == 0) ? q : (sel == 1) ? k : v;
    dst = xb + (size_t)sel * XN;
  } else {
    int j = i - 3 * NX16;      // block-uniform: NW16 % 256 == 0
    int sel = j >> 16;
    off = (size_t)(j & (NW16 - 1));
    src = (sel == 0) ? wq : (sel == 1) ? wk : wv;
    dst = wb + (size_t)sel * WN;
  }
  const float4* s4 = (const float4*)src + off * 4;
  float4 a = s4[0], b = s4[1], c = s4[2], d = s4[3];
  union { unsigned short u[8]; uint4 vv; } o0, o1;
  o0.u[0] = f2bf(a.x); o0.u[1] = f2bf(a.y); o0.u[2] = f2bf(a.z); o0.u[3] = f2bf(a.w);
  o0.u[4] = f2bf(b.x); o0.u[5] = f2bf(b.y); o0.u[6] = f2bf(b.z); o0.u[7] = f2bf(b.w);
  o1.u[0] = f2bf(c.x); o1.u[1] = f2bf(c.y); o1.u[2] = f2bf(c.z); o1.u[3] = f2bf(c.w);
  o1.u[4] = f2bf(d.x); o1.u[5] = f2bf(d.y); o1.u[6] = f2bf(d.z); o1.u[7] = f2bf(d.w);
  uint4* d4 = (uint4*)(dst + off * 16);
  d4[0] = o0.vv;
  d4[1] = o1.vv;
}

// ---------------- projection GEMM: C = relu?(X*W^T + b), bf16 output ----------------
__global__ __launch_bounds__(256) void proj_gemm_kernel(
    const unsigned short* __restrict__ Xall, const unsigned short* __restrict__ Wall,
    const float* __restrict__ b0, const float* __restrict__ b1,
    const float* __restrict__ b2, unsigned short* __restrict__ Pall) {
  const int which = blockIdx.z;
  const unsigned short* Xb = Xall + (size_t)which * XN;
  const unsigned short* Wb = Wall + (size_t)which * WN;
  const float* bias = (which == 0) ? b0 : (which == 1) ? b1 : b2;
  unsigned short* outp = Pall + (size_t)which * XN;
  const bool relu = (which < 2);
  const int bm0 = blockIdx.x * 128;
  const int bn0 = blockIdx.y * 128;

  __shared__ unsigned short As[2][128 * 32];
  __shared__ unsigned short Bs[2][128 * 32];

  const int tid = threadIdx.x;
  const int lane = tid & 63, wave = tid >> 6;
  const int wrow = (wave >> 1) * 64, wcol = (wave & 1) * 64;
  const int fr = lane & 15, fk = lane >> 4;

  f32x4 acc[4][4];
#pragma unroll
  for (int m = 0; m < 4; ++m)
#pragma unroll
    for (int n = 0; n < 4; ++n) acc[m][n] = (f32x4){0.f, 0.f, 0.f, 0.f};

  auto stage = [&](int kt, int buf) {
#pragma unroll
    for (int i = 0; i < 2; ++i) {
      int c = i * 256 + wave * 64 + lane;
      int row = c >> 2;
      int kgs = (c & 3) ^ ((row >> 1) & 3);  // inverse XOR swizzle on SOURCE
      int ldsoff = (i * 256 + wave * 64) * 16;  // bytes; wave-uniform
      gload_lds16(Xb + (size_t)(bm0 + row) * EMB + kt * 32 + kgs * 8,
                  (char*)&As[buf][0] + ldsoff);
      gload_lds16(Wb + (size_t)(bn0 + row) * EMB + kt * 32 + kgs * 8,
                  (char*)&Bs[buf][0] + ldsoff);
    }
  };

  stage(0, 0);
  __syncthreads();
  const int NK = EMB / 32;
  for (int kt = 0; kt < NK; ++kt) {
    int buf = kt & 1;
    if (kt + 1 < NK) stage(kt + 1, buf ^ 1);
    bf16x8 af[4], bfr[4];
#pragma unroll
    for (int m = 0; m < 4; ++m) {
      int row = wrow + m * 16 + fr;
      af[m] = *(const bf16x8*)((const char*)&As[buf][0] + row * 64 +
                               ((fk ^ ((row >> 1) & 3)) * 16));
    }
#pragma unroll
    for (int n = 0; n < 4; ++n) {
      int row = wcol + n * 16 + fr;
      bfr[n] = *(const bf16x8*)((const char*)&Bs[buf][0] + row * 64 +
                                ((fk ^ ((row >> 1) & 3)) * 16));
    }
#pragma unroll
    for (int m = 0; m < 4; ++m)
#pragma unroll
      for (int n = 0; n < 4; ++n)
        acc[m][n] = __builtin_amdgcn_mfma_f32_16x16x32_bf16(af[m], bfr[n],
                                                            acc[m][n], 0, 0, 0);
    __syncthreads();
  }

#pragma unroll
  for (int n = 0; n < 4; ++n) {
    int gc = bn0 + wcol + n * 16 + fr;
    float bv = bias[gc];
#pragma unroll
    for (int m = 0; m < 4; ++m) {
#pragma unroll
      for (int r = 0; r < 4; ++r) {
        int gr = bm0 + wrow + m * 16 + fk * 4 + r;
        float v = acc[m][n][r] + bv;
        if (relu) v = fmaxf(v, 0.f);
        outp[(size_t)gr * EMB + gc] = f2bf(v);
      }
    }
  }
}

// ---------------- phase 2a: per-split partial kv_[s,n,dd,m], ksum[s,n,dd] ----------------
__global__ __launch_bounds__(256) void kv_part_kernel(
    const unsigned short* __restrict__ kp, const unsigned short* __restrict__ vp,
    float* __restrict__ kvpart, float* __restrict__ kspart) {
  const int n = blockIdx.y;
  const int s = blockIdx.x;
  const int nb = n >> 4, head = n & 15;
  const int l0 = s * (L_SEQ / NSPLIT);
  __shared__ float kt[32][64];
  __shared__ float vt[32][64];
  __shared__ float wt[2][32];
  const int t = threadIdx.x;
  const int dg = t >> 3, mg = t & 7;

  float acc[4][8];
#pragma unroll
  for (int a = 0; a < 4; ++a)
#pragma unroll
    for (int b = 0; b < 8; ++b) acc[a][b] = 0.f;
  float ks[4] = {0.f, 0.f, 0.f, 0.f};

  for (int lt = l0; lt < l0 + (L_SEQ / NSPLIT); lt += 32) {
    {
      int i = t >> 3, c8 = (t & 7) * 8;
      u16x8 gk8 = *(const u16x8*)(kp + (size_t)((lt + i) * NB + nb) * EMB +
                                  head * HD + c8);
      u16x8 gv8 = *(const u16x8*)(vp + (size_t)((lt + i) * NB + nb) * EMB +
                                  head * HD + c8);
      float4 ka = {bf2f(gk8[0]), bf2f(gk8[1]), bf2f(gk8[2]), bf2f(gk8[3])};
      float4 kb = {bf2f(gk8[4]), bf2f(gk8[5]), bf2f(gk8[6]), bf2f(gk8[7])};
      float4 va = {bf2f(gv8[0]), bf2f(gv8[1]), bf2f(gv8[2]), bf2f(gv8[3])};
      float4 vb = {bf2f(gv8[4]), bf2f(gv8[5]), bf2f(gv8[6]), bf2f(gv8[7])};
      *(float4*)&kt[i][c8] = ka;
      *(float4*)&kt[i][c8 + 4] = kb;
      *(float4*)&vt[i][c8] = va;
      *(float4*)&vt[i][c8 + 4] = vb;
    }
    if (t < 32) {  // hoist trig: 2 transcendentals per tile
      float ang = ANGC * (float)(lt + t + 1);
      wt[0][t] = __sinf(ang);
      wt[1][t] = __cosf(ang);
    }
    __syncthreads();
#pragma unroll 4
    for (int i = 0; i < 32; ++i) {
      float w = wt[dg >> 4][i];   // broadcast within wave
      float4 kk4 = *(const float4*)&kt[i][(dg & 15) * 4];
      float kk[4];
      kk[0] = fmaxf(kk4.x, 0.f) * w; kk[1] = fmaxf(kk4.y, 0.f) * w;
      kk[2] = fmaxf(kk4.z, 0.f) * w; kk[3] = fmaxf(kk4.w, 0.f) * w;
      float4 v0 = *(const float4*)&vt[i][mg * 8];
      float4 v1 = *(const float4*)&vt[i][mg * 8 + 4];
      float vv[8] = {v0.x, v0.y, v0.z, v0.w, v1.x, v1.y, v1.z, v1.w};
#pragma unroll
      for (int a = 0; a < 4; ++a) {
#pragma unroll
        for (int b = 0; b < 8; ++b) acc[a][b] += kk[a] * vv[b];
        ks[a] += kk[a];
      }
    }
    __syncthreads();
  }

  float* kvn = kvpart + ((size_t)(s * 64 + n) * 128 + dg * 4) * 64 + mg * 8;
#pragma unroll
  for (int a = 0; a < 4; ++a) {
    *(float4*)&kvn[(size_t)a * 64 + 0] = *(float4*)&acc[a][0];
    *(float4*)&kvn[(size_t)a * 64 + 4] = *(float4*)&acc[a][4];
  }
  if (mg == 0) {
#pragma unroll
    for (int a = 0; a < 4; ++a)
      kspart[(size_t)(s * 64 + n) * 128 + dg * 4 + a] = ks[a];
  }
}

// ---------------- phase 2b: reduce partials -> kvT bf16 [n][m][dd] + ksum f32 ----------------
// 256 blocks: (n, mseg) — full-machine streaming.
__global__ __launch_bounds__(256) void kv_reduce_kernel(
    const float* __restrict__ kvpart, const float* __restrict__ kspart,
    unsigned short* __restrict__ kvT, float* __restrict__ ksum) {
  const int b = blockIdx.x;
  const int n = b >> 2, mseg = b & 3;   // m range [mseg*16, mseg*16+16)
  const int t = threadIdx.x;
  __shared__ float kvsum[128][17];      // [dd][m-local], padded

#pragma unroll
  for (int j = 0; j < 2; ++j) {
    int f4 = j * 256 + t;               // 0..511
    int dd = f4 >> 2, mm = f4 & 3;
    f32x4 s = (f32x4){0, 0, 0, 0};
#pragma unroll
    for (int p = 0; p < NSPLIT; ++p)
      s += *(const f32x4*)(kvpart + ((size_t)(p * 64 + n) * 128 + dd) * 64 +
                           mseg * 16 + mm * 4);
    kvsum[dd][mm * 4 + 0] = s[0];
    kvsum[dd][mm * 4 + 1] = s[1];
    kvsum[dd][mm * 4 + 2] = s[2];
    kvsum[dd][mm * 4 + 3] = s[3];
  }
  if (mseg == 0 && t < 128) {
    float s = 0.f;
#pragma unroll
    for (int p = 0; p < NSPLIT; ++p) s += kspart[(size_t)(p * 64 + n) * 128 + t];
    ksum[n * 128 + t] = s;
  }
  __syncthreads();

  // transpose-write bf16 kvT[n][m][dd]: thread -> one uint4 (8 dd) of row m
  int mloc = t >> 4, dd0 = (t & 15) * 8;
  union { unsigned short u[8]; uint4 vv; } o;
#pragma unroll
  for (int e = 0; e < 8; ++e) o.u[e] = f2bf(kvsum[dd0 + e][mloc]);
  *(uint4*)(kvT + ((size_t)n * 64 + mseg * 16 + mloc) * 128 + dd0) = o.vv;
}

// ---------------- phase 3 (MFMA): out[l,nb,head*64+m] = z * q_ . kv ----------------
__global__ __launch_bounds__(256) void out_mfma_kernel(
    const unsigned short* __restrict__ qp, const unsigned short* __restrict__ kvT,
    const float* __restrict__ ksum, float* __restrict__ out) {
  const int n = blockIdx.y;
  const int nb = n >> 4, head = n & 15;
  const int L0 = blockIdx.x * 64;
  const int t = threadIdx.x;
  const int lane = t & 63, wave = t >> 6;
  const int fr = lane & 15, fk = lane >> 4;

  __shared__ unsigned short q_lds[64 * 128];    // 16KB, granule-swizzled
  __shared__ unsigned short kvt_lds[64 * 128];  // 16KB, granule-swizzled
  __shared__ float ks_lds[128];
  __shared__ float z_lds[64];

  {  // stage q_: row j, 16 d per thread -> 4 granules (2 sin, 2 cos)
    int j = t >> 2, d0 = (t & 3) * 16;
    float ang = ANGC * (float)(L0 + j + 1);
    float sw = __sinf(ang), cw = __cosf(ang);
    const unsigned short* gq =
        qp + (size_t)((L0 + j) * NB + nb) * EMB + head * HD + d0;
    u16x8 qa = *(const u16x8*)gq;
    u16x8 qb = *(const u16x8*)(gq + 8);
    union { unsigned short u[8]; uint4 vv; } s0, s1, c0, c1;
#pragma unroll
    for (int e = 0; e < 8; ++e) {
      float fa = fmaxf(bf2f(qa[e]), 0.f);
      float fb = fmaxf(bf2f(qb[e]), 0.f);
      s0.u[e] = f2bf(fa * sw); s1.u[e] = f2bf(fb * sw);
      c0.u[e] = f2bf(fa * cw); c1.u[e] = f2bf(fb * cw);
    }
    int gs = (t & 3) * 2;  // granule base for sin part (dd = d0..d0+15)
    *(uint4*)&q_lds[(j * 16 + ((gs + 0) ^ (j & 7))) * 8] = s0.vv;
    *(uint4*)&q_lds[(j * 16 + ((gs + 1) ^ (j & 7))) * 8] = s1.vv;
    *(uint4*)&q_lds[(j * 16 + ((gs + 8) ^ (j & 7))) * 8] = c0.vv;
    *(uint4*)&q_lds[(j * 16 + ((gs + 9) ^ (j & 7))) * 8] = c1.vv;
  }
  {  // stage kvT[n]: 4 granules per thread, coalesced global reads
#pragma unroll
    for (int c = 0; c < 4; ++c) {
      int gi = t * 4 + c;
      int m = gi >> 4, g = gi & 15;
      uint4 v = *(const uint4*)(kvT + (size_t)n * 8192 + m * 128 + g * 8);
      *(uint4*)&kvt_lds[(m * 16 + (g ^ (m & 7))) * 8] = v;
    }
  }
  if (t < 128) ks_lds[t] = ksum[n * 128 + t];
  __syncthreads();

  // denominator: den[l] = sum_dd q_[l][dd] * ksum[dd]  (fp32)
  {
    int row = t >> 2, seg = t & 3;
    float sum = 0.f;
#pragma unroll
    for (int g8 = 0; g8 < 4; ++g8) {
      int g = seg * 4 + g8;
      const unsigned short* qg = &q_lds[(row * 16 + (g ^ (row & 7))) * 8];
      u16x8 qv = *(const u16x8*)qg;
#pragma unroll
      for (int e = 0; e < 8; ++e) sum += bf2f(qv[e]) * ks_lds[g * 8 + e];
    }
    sum += __shfl_xor(sum, 1);
    sum += __shfl_xor(sum, 2);
    if (seg == 0) z_lds[row] = 1.f / fmaxf(sum, 1e-4f);
  }

  // MFMA: wave w -> rows wrow..wrow+15, all 4 N-tiles
  const int wrow = wave * 16;
  f32x4 acc[4];
#pragma unroll
  for (int nt = 0; nt < 4; ++nt) acc[nt] = (f32x4){0, 0, 0, 0};
#pragma unroll
  for (int kk = 0; kk < 4; ++kk) {
    int arow = wrow + fr;
    bf16x8 af = *(const bf16x8*)&q_lds[(arow * 16 + ((kk * 4 + fk) ^ (arow & 7))) * 8];
#pragma unroll
    for (int nt = 0; nt < 4; ++nt) {
      int brow = nt * 16 + fr;
      bf16x8 bf =
          *(const bf16x8*)&kvt_lds[(brow * 16 + ((kk * 4 + fk) ^ (brow & 7))) * 8];
      acc[nt] = __builtin_amdgcn_mfma_f32_16x16x32_bf16(af, bf, acc[nt], 0, 0, 0);
    }
  }

  // epilogue: C row = fk*4+r (local), col m = nt*16+fr; multiply by z
#pragma unroll
  for (int nt = 0; nt < 4; ++nt) {
#pragma unroll
    for (int r = 0; r < 4; ++r) {
      int lrow = wrow + fk * 4 + r;
      int m = nt * 16 + fr;
      out[((size_t)(L0 + lrow) * NB + nb) * EMB + head * HD + m] =
          acc[nt][r] * z_lds[lrow];
    }
  }
}

extern "C" void kernel_launch(void* const* d_in, const int* in_sizes, int n_in,
                              void* d_out, int out_size, void* d_ws, size_t ws_size,
                              hipStream_t stream) {
  const float* query = (const float*)d_in[0];
  const float* key = (const float*)d_in[1];
  const float* value = (const float*)d_in[2];
  const float* Wq = (const float*)d_in[3];
  const float* bq = (const float*)d_in[4];
  const float* Wk = (const float*)d_in[5];
  const float* bk = (const float*)d_in[6];
  const float* Wv = (const float*)d_in[7];
  const float* bv = (const float*)d_in[8];
  float* out = (float*)d_out;

  char* ws = (char*)d_ws;
  // ws layout (bytes):
  //   xb:   0         .. 50331648   (bf16 q/k/v inputs)  [dead after proj]
  //   wb:   50331648  .. 56623104   (bf16 Wq/Wk/Wv)      [dead after proj]
  //   proj: 56623104  .. 106954752  (bf16 q/k/v projections)
  //   kvT:  106954752 .. 108003328  (bf16 [n][m][dd])
  //   ksb:  108003328 .. 108036096  (f32  [n][dd])
  //   kvpart/kspart ALIAS xb (34 MB <= 50 MB, xb dead by then; same stream)
  const size_t need = 3 * XN * 2 + 3 * WN * 2 + 3 * XN * 2 +
                      (size_t)64 * 64 * 128 * 2 + (size_t)64 * 128 * 4;
  if (ws_size < need) return;  // refuse to corrupt memory; clean test failure

  unsigned short* xb = (unsigned short*)ws;
  unsigned short* wb = (unsigned short*)(ws + 3 * XN * 2);
  unsigned short* proj = (unsigned short*)(ws + 3 * XN * 2 + 3 * WN * 2);
  unsigned short* kvT = (unsigned short*)(ws + 3 * XN * 2 + 3 * WN * 2 + 3 * XN * 2);
  float* ksb = (float*)(ws + 3 * XN * 2 + 3 * WN * 2 + 3 * XN * 2 +
                        (size_t)64 * 64 * 128 * 2);
  float* kvpart = (float*)ws;                                         // 32MB
  float* kspart = (float*)(ws + (size_t)NSPLIT * 64 * 128 * 64 * 4);  // 512KB

  const int total16 = 3 * NX16 + 3 * NW16;  // 1769472, divisible by 256
  cvt_all_kernel<<<total16 / 256, 256, 0, stream>>>(query, key, value, Wq, Wk, Wv,
                                                    xb, wb);
  proj_gemm_kernel<<<dim3(64, 8, 3), 256, 0, stream>>>(xb, wb, bq, bk, bv, proj);
  kv_part_kernel<<<dim3(NSPLIT, 64), 256, 0, stream>>>(proj + 1 * XN, proj + 2 * XN,
                                                       kvpart, kspart);
  kv_reduce_kernel<<<256, 256, 0, stream>>>(kvpart, kspart, kvT, ksb);
  out_mfma_kernel<<<dim3(32, 64), 256, 0, stream>>>(proj, kvT, ksb, out);
}